// Round 5
// baseline (70.400 us; speedup 1.0000x reference)
//
#include <hip/hip_runtime.h>

#define WAVE 64

__device__ __forceinline__ int rf(int x) { return __builtin_amdgcn_readfirstlane(x); }
__device__ __forceinline__ float bperm_f(int addr, float v) {
    return __int_as_float(__builtin_amdgcn_ds_bpermute(addr, __float_as_int(v)));
}
__device__ __forceinline__ int bperm_i(int addr, int v) {
    return __builtin_amdgcn_ds_bpermute(addr, v);
}

// One wave per pair.
// Fast path (c == 1.0):
//   Stage 1 — branch-free prefix-match screen: sentinel-mask tokens outside
//   the la x lb prefix, OR all 64 ballot masks (fully unrolled, no
//   loop-carried dependency). If no match exists in the prefix (~90% of
//   pairs at V=10000), distance == max(la, lb) exactly -> early out.
//   Stage 2 — Myers bit-parallel Levenshtein for the ~10% remainder, with
//   sparse collapsed step (Eq|Mv)==0 -> Pv<<=1 and end-only scoring
//   score = n + pcnt(Pv&mask) - pcnt(Mv&mask).
// Fallback (general c): R2's anti-diagonal float DP (validated absmax=0).
__global__ __launch_bounds__(256) void edit_distance_kernel(
    const int* __restrict__ t1, const int* __restrict__ t2,
    const int* __restrict__ len1, const int* __restrict__ len2,
    const float* __restrict__ subc, float* __restrict__ out, int B)
{
    const int tid  = blockIdx.x * blockDim.x + threadIdx.x;
    const int pair = tid >> 6;
    const int lane = tid & (WAVE - 1);
    if (pair >= B) return;

    const float c      = subc[0];
    const int   a_tok  = t1[pair * 64 + lane];
    const int   b_tok  = t2[pair * 64 + lane];
    const int   la     = rf(len1[pair]);
    const int   lb     = rf(len2[pair]);
    const bool  unit_c = (rf(__float_as_int(c)) == __float_as_int(1.0f));

    if (unit_c) {
        const bool sw  = lb > la;
        const int  m   = sw ? lb : la;        // pattern length = max(la,lb)
        const int  n   = sw ? la : lb;        // text length    = min(la,lb)
        const int  pat = sw ? b_tok : a_tok;  // lane i holds pattern[i]
        const int  txt = sw ? a_tok : b_tok;  // lane j holds text[j]

        // Sentinel-mask outside the prefix: -2 / -1 can never equal a real
        // token (tokens are in [0, V)) nor each other.
        const int pat_m = (lane < m) ? pat : -2;
        const int txt_m = (lane < n) ? txt : -1;

        // ---- Stage 1: branch-free screen (64 independent ballot-ORs) ----
        unsigned long long any = 0ull;
#pragma unroll
        for (int j = 0; j < 64; ++j) {
            const int bj = __builtin_amdgcn_readlane(txt_m, j);
            any |= __ballot(pat_m == bj);
        }

        if (any == 0ull) {                    // no match in prefix
            if (lane == 0) out[pair] = (float)m;   // distance = max(la,lb)
            return;
        }

        // ---- Stage 2: Myers bit-parallel (matches exist) ----
        unsigned long long Pv = ~0ull, Mv = 0ull;
        for (int j = 0; j < n; ++j) {
            const int bj = __builtin_amdgcn_readlane(txt, j);
            const unsigned long long Eq = __ballot(pat_m == bj);
            if ((Eq | Mv) == 0ull) {
                Pv <<= 1;                     // exact collapsed update
            } else {
                const unsigned long long Xv = Eq | Mv;
                const unsigned long long Xh = (((Eq & Pv) + Pv) ^ Pv) | Eq;
                unsigned long long Ph = Mv | ~(Xh | Pv);
                const unsigned long long Mh = Pv & Xh;
                Ph = (Ph << 1) | 1ull;
                Pv = (Mh << 1) | ~(Xv | Ph);
                Mv = Ph & Xv;
            }
        }
        const unsigned long long mask = ~0ull >> (64 - m);  // m>=1 here
        const int score = n + __popcll(Pv & mask) - __popcll(Mv & mask);
        if (lane == 0) out[pair] = (float)score;
    } else {
        // ---------- general-cost anti-diagonal DP (R2) ----------
        const int rotaddr = ((lane + 63) & 63) << 2;
        int bcur = bperm_i(((64 - lane) & 63) << 2, b_tok);
        const int  tmax   = rf(la + lb - 1);
        const bool lane0  = (lane == 0);
        const int  target = lb + lane - 1;

        float cur   = (float)(lane + 1);
        float diagn = 0.f;
        float saved = 0.f;
        float ft    = 0.f;

        for (int t = 0; t < tmax; ++t) {
            float up   = bperm_f(rotaddr, cur);
            float diag = diagn;
            if (lane0) { up = ft + 1.f; diag = ft; }

            const float cost = (a_tok == bcur) ? 0.f : c;
            const float v = fminf(fminf(up, cur) + 1.f, diag + cost);

            if (t >= lane) {
                cur = v;
                if (t == target) saved = v;
            }
            diagn = up;
            bcur  = bperm_i(rotaddr, bcur);
            ft   += 1.f;
        }

        int src = (la > 0) ? (la - 1) : 0;
        float ans = __shfl(saved, src, WAVE);
        if (la == 0)      ans = (float)lb;
        else if (lb == 0) ans = (float)la;

        if (lane == 0) out[pair] = ans;
    }
}

extern "C" void kernel_launch(void* const* d_in, const int* in_sizes, int n_in,
                              void* d_out, int out_size, void* d_ws, size_t ws_size,
                              hipStream_t stream) {
    const int*   tokens1 = (const int*)d_in[0];
    const int*   tokens2 = (const int*)d_in[1];
    const int*   len1    = (const int*)d_in[2];
    const int*   len2    = (const int*)d_in[3];
    const float* subc    = (const float*)d_in[4];
    float*       out     = (float*)d_out;

    const int B = in_sizes[2];           // 8192
    const int threads = 256;             // 4 waves (pairs) per block
    const int blocks  = (B * WAVE + threads - 1) / threads;
    edit_distance_kernel<<<blocks, threads, 0, stream>>>(
        tokens1, tokens2, len1, len2, subc, out, B);
}

// Round 6
// 68.604 us; speedup vs baseline: 1.0262x; 1.0262x over previous
//
#include <hip/hip_runtime.h>

#define WAVE 64

__device__ __forceinline__ int rf(int x) { return __builtin_amdgcn_readfirstlane(x); }
__device__ __forceinline__ float bperm_f(int addr, float v) {
    return __int_as_float(__builtin_amdgcn_ds_bpermute(addr, __float_as_int(v)));
}
__device__ __forceinline__ int bperm_i(int addr, int v) {
    return __builtin_amdgcn_ds_bpermute(addr, v);
}

// One wave per pair.
// Fast path (c == 1.0):
//   Pass 1 (j < n only): ballot-screen building colmask (bit j = any pattern
//   match in column j). colmask==0 (~90% of pairs) -> dist = max(la,lb).
//   Pass 2 (survivors): run-skipping Myers — runs of empty columns while
//   Mv==0 collapse exactly to Pv <<= z; Eq=0 steps while Mv!=0 use the
//   reduced 3-op update; only match columns (mean ~1.3) pay the full step.
//   End-only score: n + pcnt(Pv&lowmask(m)) - pcnt(Mv&lowmask(m)).
// Fallback (general c): R2's anti-diagonal float DP (validated absmax=0).
__global__ __launch_bounds__(256) void edit_distance_kernel(
    const int* __restrict__ t1, const int* __restrict__ t2,
    const int* __restrict__ len1, const int* __restrict__ len2,
    const float* __restrict__ subc, float* __restrict__ out, int B)
{
    const int tid  = blockIdx.x * blockDim.x + threadIdx.x;
    const int pair = tid >> 6;
    const int lane = tid & (WAVE - 1);
    if (pair >= B) return;

    const float c      = subc[0];
    const int   a_tok  = t1[pair * 64 + lane];
    const int   b_tok  = t2[pair * 64 + lane];
    const int   la     = rf(len1[pair]);
    const int   lb     = rf(len2[pair]);
    const bool  unit_c = (rf(__float_as_int(c)) == __float_as_int(1.0f));

    if (unit_c) {
        const bool sw  = lb > la;
        const int  m   = sw ? lb : la;        // pattern length = max(la,lb)
        const int  n   = sw ? la : lb;        // text length    = min(la,lb)
        const int  pat = sw ? b_tok : a_tok;  // lane i holds pattern[i]
        const int  txt = sw ? a_tok : b_tok;  // lane j holds text[j]
        // Rows >= m must never match (tokens are >= 0, so -2 is safe).
        const int  pat_m = (lane < m) ? pat : -2;

        // ---- Pass 1: screen columns j<n, build match-column mask ----
        unsigned long long colmask = 0ull;
        for (int j = 0; j < n; ++j) {
            const int bj = __builtin_amdgcn_readlane(txt, j);
            const unsigned long long Eq = __ballot(pat_m == bj);
            colmask |= (unsigned long long)(Eq != 0ull) << j;
        }

        if (colmask == 0ull) {                // no match in prefix (or n==0)
            if (lane == 0) out[pair] = (float)m;
            return;
        }

        // ---- Pass 2: run-skipping Myers over match columns ----
        unsigned long long Pv = ~0ull, Mv = 0ull;
        unsigned long long cols = colmask;
        int jcur = 0;
        while (cols) {
            const int jn = __builtin_ctzll(cols);
            cols &= cols - 1;
            // columns jcur..jn-1 have Eq == 0
            while (jcur < jn && Mv != 0ull) {   // reduced Eq=0 step
                unsigned long long Ph = ((Mv | ~Pv) << 1) | 1ull;
                const unsigned long long Pv2 = ~(Mv | Ph);
                Mv = Ph & Mv;
                Pv = Pv2;
                ++jcur;
            }
            if (jcur < jn) { Pv <<= (jn - jcur); jcur = jn; }  // Mv==0 run skip
            // full step at match column jn
            const int bj = __builtin_amdgcn_readlane(txt, jn);
            const unsigned long long Eq = __ballot(pat_m == bj);
            const unsigned long long Xv = Eq | Mv;
            const unsigned long long Xh = (((Eq & Pv) + Pv) ^ Pv) | Eq;
            unsigned long long Ph = Mv | ~(Xh | Pv);
            const unsigned long long Mh = Pv & Xh;
            Ph = (Ph << 1) | 1ull;
            Pv = (Mh << 1) | ~(Xv | Ph);
            Mv = Ph & Xv;
            jcur = jn + 1;
        }
        // tail columns jcur..n-1 (all Eq == 0)
        while (Mv != 0ull && jcur < n) {
            unsigned long long Ph = ((Mv | ~Pv) << 1) | 1ull;
            const unsigned long long Pv2 = ~(Mv | Ph);
            Mv = Ph & Mv;
            Pv = Pv2;
            ++jcur;
        }
        Pv <<= (n - jcur);                     // Mv==0 here

        const unsigned long long mask = ~0ull >> (64 - m);   // m>=1 (colmask!=0)
        const int score = n + __popcll(Pv & mask) - __popcll(Mv & mask);
        if (lane == 0) out[pair] = (float)score;
    } else {
        // ---------- general-cost anti-diagonal DP (R2) ----------
        const int rotaddr = ((lane + 63) & 63) << 2;
        int bcur = bperm_i(((64 - lane) & 63) << 2, b_tok);
        const int  tmax   = rf(la + lb - 1);
        const bool lane0  = (lane == 0);
        const int  target = lb + lane - 1;

        float cur   = (float)(lane + 1);
        float diagn = 0.f;
        float saved = 0.f;
        float ft    = 0.f;

        for (int t = 0; t < tmax; ++t) {
            float up   = bperm_f(rotaddr, cur);
            float diag = diagn;
            if (lane0) { up = ft + 1.f; diag = ft; }

            const float cost = (a_tok == bcur) ? 0.f : c;
            const float v = fminf(fminf(up, cur) + 1.f, diag + cost);

            if (t >= lane) {
                cur = v;
                if (t == target) saved = v;
            }
            diagn = up;
            bcur  = bperm_i(rotaddr, bcur);
            ft   += 1.f;
        }

        int src = (la > 0) ? (la - 1) : 0;
        float ans = __shfl(saved, src, WAVE);
        if (la == 0)      ans = (float)lb;
        else if (lb == 0) ans = (float)la;

        if (lane == 0) out[pair] = ans;
    }
}

extern "C" void kernel_launch(void* const* d_in, const int* in_sizes, int n_in,
                              void* d_out, int out_size, void* d_ws, size_t ws_size,
                              hipStream_t stream) {
    const int*   tokens1 = (const int*)d_in[0];
    const int*   tokens2 = (const int*)d_in[1];
    const int*   len1    = (const int*)d_in[2];
    const int*   len2    = (const int*)d_in[3];
    const float* subc    = (const float*)d_in[4];
    float*       out     = (float*)d_out;

    const int B = in_sizes[2];           // 8192
    const int threads = 256;             // 4 waves (pairs) per block
    const int blocks  = (B * WAVE + threads - 1) / threads;
    edit_distance_kernel<<<blocks, threads, 0, stream>>>(
        tokens1, tokens2, len1, len2, subc, out, B);
}